// Round 8
// baseline (214.311 us; speedup 1.0000x reference)
//
#include <hip/hip_runtime.h>
#include <cstdint>
#include <cstddef>

typedef __attribute__((ext_vector_type(8))) short bf16x8;
typedef __attribute__((ext_vector_type(4))) float f32x4;

#define S_    2048
#define D_    1024
#define F_    2048
#define O_    1024
#define E_    8
#define KCAP  256
#define ROWS  512           // 2 batches * KCAP per expert
#define NTOK  4096          // B*S

#define BM 64
#define BN 64
#define BK 64
#define TILE_ELEMS (BM * BK)

// ---------- bf16 helpers ----------
__device__ __forceinline__ unsigned short f2bf(float f) {
  unsigned int u = __float_as_uint(f);
  u = (u + 0x7fffu + ((u >> 16) & 1u)) >> 16;   // RNE
  return (unsigned short)u;
}
__device__ __forceinline__ float bf2f(unsigned short h) {
  return __uint_as_float(((unsigned int)h) << 16);
}

// ---------- async global->LDS, 16B per lane, wave-uniform LDS base ----------
__device__ __forceinline__ void gload16(void* lds, const void* g) {
  auto gp = (__attribute__((address_space(1))) unsigned int*)(uintptr_t)g;
  auto lp = (__attribute__((address_space(3))) unsigned int*)(unsigned int)(uintptr_t)lds;
  __builtin_amdgcn_global_load_lds(gp, lp, 16, 0, 0);
}

// ---------- gating: logits (fp64 accum) + softmax probs + x->bf16 ----------
__global__ void gating_kernel(const float* __restrict__ x, const float* __restrict__ wg,
                              float* __restrict__ logits, float* __restrict__ probs,
                              unsigned short* __restrict__ xb) {
  const int wave = threadIdx.x >> 6, lane = threadIdx.x & 63;
  const int t = blockIdx.x * 4 + wave;
  const float* xr = x + (size_t)t * D_;
  double acc[8] = {0, 0, 0, 0, 0, 0, 0, 0};
  const int d0 = lane * 16;
#pragma unroll
  for (int i = 0; i < 4; i++) {
    float4 xv = *(const float4*)&xr[d0 + i * 4];
    union { ushort4 u4; unsigned short u[4]; } cv;
    cv.u[0] = f2bf(xv.x); cv.u[1] = f2bf(xv.y); cv.u[2] = f2bf(xv.z); cv.u[3] = f2bf(xv.w);
    *(ushort4*)&xb[(size_t)t * D_ + d0 + i * 4] = cv.u4;
    float xs[4] = {xv.x, xv.y, xv.z, xv.w};
#pragma unroll
    for (int j = 0; j < 4; j++) {
      const float4* wr = (const float4*)&wg[(size_t)(d0 + i * 4 + j) * 8];
      float4 w0 = wr[0], w1v = wr[1];
      double xd = (double)xs[j];
      acc[0] += xd * (double)w0.x;  acc[1] += xd * (double)w0.y;
      acc[2] += xd * (double)w0.z;  acc[3] += xd * (double)w0.w;
      acc[4] += xd * (double)w1v.x; acc[5] += xd * (double)w1v.y;
      acc[6] += xd * (double)w1v.z; acc[7] += xd * (double)w1v.w;
    }
  }
#pragma unroll
  for (int off = 32; off; off >>= 1) {
#pragma unroll
    for (int e = 0; e < 8; e++) acc[e] += __shfl_down(acc[e], off);
  }
  if (lane == 0) {
    double m = acc[0];
    for (int e = 1; e < 8; e++) m = acc[e] > m ? acc[e] : m;
    double p[8]; double s = 0;
    for (int e = 0; e < 8; e++) { p[e] = exp(acc[e] - m); s += p[e]; }
    const double inv = 1.0 / s;
    for (int e = 0; e < 8; e++) {
      logits[(size_t)t * 8 + e] = (float)acc[e];
      probs [(size_t)t * 8 + e] = (float)(p[e] * inv);
    }
  }
}

// ---------- per-expert transpose + fp32->bf16: out[C][R] = in[R][C] ----------
__global__ void transpose_cvt_kernel(const float* __restrict__ in, unsigned short* __restrict__ out,
                                     const int R, const int C) {
  __shared__ float t[64][65];
  const int e = blockIdx.z;
  const float* inp = in + (size_t)e * R * C;
  unsigned short* outp = out + (size_t)e * R * C;
  const int r0 = blockIdx.y * 64, c0 = blockIdx.x * 64;
  const int tid = threadIdx.x;
  const int lr = tid >> 4;          // 0..15
  const int lc = (tid & 15) * 4;    // 0..60
#pragma unroll
  for (int i = 0; i < 4; i++) {
    const int r = lr + i * 16;
    const float4 v = *(const float4*)&inp[(size_t)(r0 + r) * C + c0 + lc];
    t[r][lc] = v.x; t[r][lc + 1] = v.y; t[r][lc + 2] = v.z; t[r][lc + 3] = v.w;
  }
  __syncthreads();
#pragma unroll
  for (int i = 0; i < 4; i++) {
    const int oc = lr + i * 16;     // output row (a C-index)
    union { ushort4 u4; unsigned short u[4]; } u;
#pragma unroll
    for (int j = 0; j < 4; j++) u.u[j] = f2bf(t[lc + j][oc]);
    *(ushort4*)&outp[(size_t)(c0 + oc) * R + r0 + lc] = u.u4;
  }
}

// ---------- expert-choice top-k: u32-key rank counting, 3-region loop ----------
__global__ void topk_kernel(const float* __restrict__ logits, const float* __restrict__ probs,
                            int* __restrict__ sel, float* __restrict__ gate) {
  __shared__ unsigned int keys[S_];
  const int idx = blockIdx.x;       // 0..127 : (b,e) x 8 segments
  const int seg = idx & 7;
  const int be = idx >> 3;          // 0..15
  const int b = be >> 3;            // 0..1
  const int e = be & 7;
  const int tid = threadIdx.x;
  for (int i = tid; i < S_; i += 256) {
    unsigned int u = __float_as_uint(logits[((size_t)(b * S_ + i)) * E_ + e]);
    keys[i] = u ^ ((u & 0x80000000u) ? 0xFFFFFFFFu : 0x80000000u);
  }
  __syncthreads();
  const int s = seg * 256 + tid;
  const unsigned int vk = keys[s];
  const int wave = tid >> 6;
  const int W0 = seg * 256 + wave * 64;
  int rank = 0;
#pragma unroll 4
  for (int i = 0; i < W0; i += 4) {
    const uint4 kv = *(const uint4*)&keys[i];
    rank += (kv.x >= vk) + (kv.y >= vk) + (kv.z >= vk) + (kv.w >= vk);
  }
#pragma unroll
  for (int j = 0; j < 64; j++) {
    const int i = W0 + j;
    const unsigned int kv = keys[i];
    rank += (kv > vk) || (kv == vk && i < s);
  }
#pragma unroll 4
  for (int i = W0 + 64; i < S_; i += 4) {
    const uint4 kv = *(const uint4*)&keys[i];
    rank += (kv.x > vk) + (kv.y > vk) + (kv.z > vk) + (kv.w > vk);
  }
  if (rank < KCAP) {
    sel [e * ROWS + b * KCAP + rank] = b * S_ + s;
    gate[e * ROWS + b * KCAP + rank] = probs[((size_t)(b * S_ + s)) * E_ + e];
  }
}

// ====================== DARK: hybrid gemm1, scratch-bug fixed ======================
// 64m x 128n, 4 waves (wave-tile 64x32). A in LDS (gload16+swizzle, dbuf);
// B direct global->reg with NAMED double buffers (bregA/bregB) in a 2-step
// unrolled loop so all register indices are compile-time (rule #20).
__global__ __launch_bounds__(256, 4) void gemm1_hyb_kernel(
    const unsigned short* __restrict__ xb, const unsigned short* __restrict__ w1t,
    const float* __restrict__ b1, const int* __restrict__ sel,
    unsigned short* __restrict__ hbuf) {
  __shared__ unsigned short As[2][64 * 64];  // 16 KB
  const int bid = blockIdx.x;                // 1024 blocks
  const int lid = (bid & 7) * 128 + (bid >> 3);
  const int e   = lid >> 7;
  const int rem = lid & 127;
  const int m0  = (rem & 7) * 64;
  const int n0  = (rem >> 3) * 128;
  const int tid = threadIdx.x;
  const int wave = tid >> 6, lane = tid & 63;
  const int fr = lane & 15;
  const int kq = lane >> 4;

  const unsigned short* a_src[2];
#pragma unroll
  for (int j = 0; j < 2; j++) {
    const int r = wave * 16 + j * 8 + (lane >> 3);
    const int chunk = (lane & 7) ^ (r & 7);
    a_src[j] = xb + (size_t)sel[e * ROWS + m0 + r] * D_ + chunk * 8;
  }
  const unsigned short* bptr = w1t + ((size_t)(e * F_ + n0 + wave * 32 + fr)) * D_ + kq * 8;

  f32x4 acc[4][2];
#pragma unroll
  for (int mi = 0; mi < 4; mi++)
#pragma unroll
    for (int nj = 0; nj < 2; nj++) acc[mi][nj] = (f32x4){0.f, 0.f, 0.f, 0.f};

  bf16x8 bregA[2][2], bregB[2][2];   // static names, never runtime-indexed

  auto stageA = [&](int buf, int t) {
    const int k0 = t * BK;
    gload16(&As[buf][(wave * 16 + 0) * 64], a_src[0] + k0);
    gload16(&As[buf][(wave * 16 + 8) * 64], a_src[1] + k0);
  };
#define LOADB(dst, t)                                                           \
  {                                                                             \
    const size_t k0_ = (size_t)(t) * BK;                                        \
    dst[0][0] = *(const bf16x8*)(bptr + k0_);                                   \
    dst[0][1] = *(const bf16x8*)(bptr + (size_t)16 * D_ + k0_);                 \
    dst[1][0] = *(const bf16x8*)(bptr + k0_ + 32);                              \
    dst[1][1] = *(const bf16x8*)(bptr + (size_t)16 * D_ + k0_ + 32);            \
  }
#define COMPUTE(abuf, breg)                                                     \
  {                                                                             \
    const unsigned short* Ab = As[abuf];                                        \
    _Pragma("unroll")                                                           \
    for (int kk = 0; kk < 2; kk++) {                                            \
      const int q = kk * 4 + kq;                                                \
      bf16x8 a[4];                                                              \
      _Pragma("unroll")                                                         \
      for (int mi = 0; mi < 4; mi++) {                                          \
        const int r = mi * 16 + fr;                                             \
        a[mi] = *(const bf16x8*)&Ab[r * 64 + ((q ^ (r & 7)) * 8)];              \
      }                                                                         \
      _Pragma("unroll")                                                         \
      for (int mi = 0; mi < 4; mi++) {                                          \
        acc[mi][0] = __builtin_amdgcn_mfma_f32_16x16x32_bf16(a[mi], breg[kk][0], acc[mi][0], 0, 0, 0); \
        acc[mi][1] = __builtin_amdgcn_mfma_f32_16x16x32_bf16(a[mi], breg[kk][1], acc[mi][1], 0, 0, 0); \
      }                                                                         \
    }                                                                           \
  }

  const int NT = D_ / BK;   // 16
  stageA(0, 0);
  stageA(1, 1);
  LOADB(bregA, 0);
#pragma unroll 1
  for (int tp = 0; tp < NT; tp += 2) {
    // even step tp: compute As[0]/bregA, prefetch B(tp+1)->bregB, stage A(tp+2)->buf0
    LOADB(bregB, tp + 1);
    if (tp == 0) asm volatile("s_waitcnt vmcnt(4)" ::: "memory");
    else         asm volatile("s_waitcnt vmcnt(6)" ::: "memory");
    asm volatile("s_barrier" ::: "memory");
    COMPUTE(0, bregA);
    asm volatile("s_barrier" ::: "memory");
    if (tp + 2 < NT) stageA(0, tp + 2);
    // odd step tp+1: compute As[1]/bregB, prefetch B(tp+2)->bregA, stage A(tp+3)->buf1
    if (tp + 2 < NT) LOADB(bregA, tp + 2);
    if (tp + 1 == NT - 1) asm volatile("s_waitcnt vmcnt(0)" ::: "memory");
    else                  asm volatile("s_waitcnt vmcnt(6)" ::: "memory");
    asm volatile("s_barrier" ::: "memory");
    COMPUTE(1, bregB);
    if (tp + 2 < NT) {
      asm volatile("s_barrier" ::: "memory");
      stageA(1, tp + 3);
    }
  }
#undef LOADB
#undef COMPUTE

#pragma unroll
  for (int mi = 0; mi < 4; mi++)
#pragma unroll
    for (int nj = 0; nj < 2; nj++)
#pragma unroll
      for (int rg = 0; rg < 4; rg++) {
        const int row = m0 + mi * 16 + kq * 4 + rg;
        const int col = n0 + wave * 32 + nj * 16 + fr;
        float v = acc[mi][nj][rg] + b1[e * F_ + col];
        v = 0.5f * v * (1.0f + erff(v * 0.70710678118654752f));
        hbuf[((size_t)e * ROWS + row) * F_ + col] = f2bf(v);
      }
}

// ====================== CANONICAL GEMM1 (R3, proven 46us) ======================
__global__ __launch_bounds__(256, 4) void gemm1_kernel(
    const unsigned short* __restrict__ xb,   // [NTOK][D_]
    const unsigned short* __restrict__ w1t,  // [E][F_][D_]
    const float* __restrict__ b1,            // [E][F_]
    const int* __restrict__ sel,             // [E][ROWS]
    unsigned short* __restrict__ hbuf) {     // [E][ROWS][F_]
  __shared__ unsigned short As[2 * TILE_ELEMS];
  __shared__ unsigned short Bs[2 * TILE_ELEMS];
  const int bid = blockIdx.x;
  const int lid = (bid & 7) * 256 + (bid >> 3);
  const int e   = lid >> 8;
  const int rem = lid & 255;
  const int n0  = (rem >> 3) * BN;
  const int m0  = (rem & 7) * BM;
  const int tid = threadIdx.x;
  const int wave = tid >> 6, lane = tid & 63;
  const int wr = wave >> 1, wc = wave & 1;

  const int srow = lane >> 3;
  const int schunk = (lane & 7) ^ srow;
  const unsigned short* asrc[2];
  const unsigned short* bsrc[2];
#pragma unroll
  for (int j = 0; j < 2; j++) {
    const int r = wave * 16 + j * 8 + srow;
    const int tok = sel[e * ROWS + m0 + r];
    asrc[j] = xb + (size_t)tok * D_ + schunk * 8;
    bsrc[j] = w1t + ((size_t)e * F_ + n0 + r) * D_ + schunk * 8;
  }

  f32x4 acc[2][2];
#pragma unroll
  for (int mi = 0; mi < 2; mi++)
#pragma unroll
    for (int nj = 0; nj < 2; nj++) acc[mi][nj] = (f32x4){0.f, 0.f, 0.f, 0.f};

  const int fr = lane & 15;

  auto stage = [&](int buf, int k0) {
#pragma unroll
    for (int j = 0; j < 2; j++) {
      gload16(&As[buf * TILE_ELEMS + (wave * 16 + j * 8) * BK], asrc[j] + k0);
      gload16(&Bs[buf * TILE_ELEMS + (wave * 16 + j * 8) * BK], bsrc[j] + k0);
    }
  };
  auto compute = [&](int buf) {
    const unsigned short* Ab = &As[buf * TILE_ELEMS];
    const unsigned short* Bb = &Bs[buf * TILE_ELEMS];
    bf16x8 a[2][2], b[2][2];
#pragma unroll
    for (int kk = 0; kk < 2; kk++) {
      const int xch = ((kk * 4 + (lane >> 4)) ^ (lane & 7)) * 8;
#pragma unroll
      for (int mi = 0; mi < 2; mi++)
        a[kk][mi] = *(const bf16x8*)&Ab[(wr * 32 + mi * 16 + fr) * BK + xch];
#pragma unroll
      for (int nj = 0; nj < 2; nj++)
        b[kk][nj] = *(const bf16x8*)&Bb[(wc * 32 + nj * 16 + fr) * BK + xch];
    }
#pragma unroll
    for (int kk = 0; kk < 2; kk++)
#pragma unroll
      for (int mi = 0; mi < 2; mi++)
#pragma unroll
        for (int nj = 0; nj < 2; nj++)
          acc[mi][nj] = __builtin_amdgcn_mfma_f32_16x16x32_bf16(a[kk][mi], b[kk][nj], acc[mi][nj], 0, 0, 0);
  };

  stage(0, 0);
  __syncthreads();
  int cur = 0;
  for (int t = 0; t < D_ / BK - 1; t++) {
    stage(cur ^ 1, (t + 1) * BK);
    compute(cur);
    __syncthreads();
    cur ^= 1;
  }
  compute(cur);

  const int lr = (lane >> 4) * 4;
#pragma unroll
  for (int mi = 0; mi < 2; mi++)
#pragma unroll
    for (int nj = 0; nj < 2; nj++)
#pragma unroll
      for (int rg = 0; rg < 4; rg++) {
        const int row = m0 + wr * 32 + mi * 16 + lr + rg;
        const int col = n0 + wc * 32 + nj * 16 + fr;
        float v = acc[mi][nj][rg] + b1[e * F_ + col];
        v = 0.5f * v * (1.0f + erff(v * 0.70710678118654752f));   // exact GELU
        hbuf[((size_t)e * ROWS + row) * F_ + col] = f2bf(v);
      }
}

// ---------- row LayerNorm over F_, in place on bf16 h ----------
__global__ void ln_kernel(unsigned short* __restrict__ hbuf,
                          const float* __restrict__ g_ln, const float* __restrict__ b_ln) {
  const int row = blockIdx.x;          // 0..E_*ROWS-1
  const int e = row >> 9;
  unsigned short* hr = hbuf + (size_t)row * F_;
  const int tid = threadIdx.x;
  union { bf16x8 v; unsigned short u[8]; } u;
  u.v = *(const bf16x8*)&hr[tid * 8];
  float vals[8]; float s1 = 0.f, s2 = 0.f;
#pragma unroll
  for (int j = 0; j < 8; j++) { float f = bf2f(u.u[j]); vals[j] = f; s1 += f; s2 += f * f; }
#pragma unroll
  for (int off = 32; off; off >>= 1) { s1 += __shfl_down(s1, off); s2 += __shfl_down(s2, off); }
  __shared__ float rs[8];
  const int wave = tid >> 6, lane = tid & 63;
  if (lane == 0) { rs[wave] = s1; rs[wave + 4] = s2; }
  __syncthreads();
  const float t1 = rs[0] + rs[1] + rs[2] + rs[3];
  const float t2 = rs[4] + rs[5] + rs[6] + rs[7];
  const float mu = t1 * (1.f / F_);
  const float var = t2 * (1.f / F_) - mu * mu;   // biased var (jnp.var)
  const float rstd = rsqrtf(var + 1e-5f);
  const float4* gl4 = (const float4*)(g_ln + (size_t)e * F_ + tid * 8);
  const float4* bl4 = (const float4*)(b_ln + (size_t)e * F_ + tid * 8);
  float4 g0 = gl4[0], g1 = gl4[1], bb0 = bl4[0], bb1 = bl4[1];
  float gs[8] = {g0.x, g0.y, g0.z, g0.w, g1.x, g1.y, g1.z, g1.w};
  float bs[8] = {bb0.x, bb0.y, bb0.z, bb0.w, bb1.x, bb1.y, bb1.z, bb1.w};
  union { bf16x8 v; unsigned short u[8]; } o;
#pragma unroll
  for (int j = 0; j < 8; j++)
    o.u[j] = f2bf((vals[j] - mu) * rstd * gs[j] + bs[j]);
  *(bf16x8*)&hr[tid * 8] = o.v;
}

// ====================== GEMM2: R3 structure + split-K x2, 2048 blocks ======================
__global__ __launch_bounds__(256, 4) void gemm2_kernel(
    const unsigned short* __restrict__ hbuf, // [E][ROWS][F_]
    const unsigned short* __restrict__ w2t,  // [E][O_][F_]
    const float* __restrict__ b2,            // [E][O_]
    const int* __restrict__ sel, const float* __restrict__ gate,
    float* __restrict__ out) {               // [NTOK][O_]
  __shared__ unsigned short As[2 * TILE_ELEMS];
  __shared__ unsigned short Bs[2 * TILE_ELEMS];
  // 2048 blocks = 8 XCDs x 256; expert-per-XCD
  const int bid = blockIdx.x;
  const int lid = (bid & 7) * 256 + (bid >> 3);
  const int e     = lid >> 8;
  const int rem   = lid & 255;
  const int khalf = rem & 1;              // split-K x2
  const int m0    = ((rem >> 1) & 7) * BM;
  const int n0    = (rem >> 4) * BN;      // 16 O panels
  const int koff  = khalf * (F_ / 2);     // 1024
  const int tid = threadIdx.x;
  const int wave = tid >> 6, lane = tid & 63;
  const int wr = wave >> 1, wc = wave & 1;

  const int srow = lane >> 3;
  const int schunk = (lane & 7) ^ srow;
  const unsigned short* asrc[2];
  const unsigned short* bsrc[2];
#pragma unroll
  for (int j = 0; j < 2; j++) {
    const int r = wave * 16 + j * 8 + srow;
    asrc[j] = hbuf + ((size_t)e * ROWS + m0 + r) * F_ + koff + schunk * 8;
    bsrc[j] = w2t + ((size_t)e * O_ + n0 + r) * F_ + koff + schunk * 8;
  }

  f32x4 acc[2][2];
#pragma unroll
  for (int mi = 0; mi < 2; mi++)
#pragma unroll
    for (int nj = 0; nj < 2; nj++) acc[mi][nj] = (f32x4){0.f, 0.f, 0.f, 0.f};

  const int fr = lane & 15;

  auto stage = [&](int buf, int k0) {
#pragma unroll
    for (int j = 0; j < 2; j++) {
      gload16(&As[buf * TILE_ELEMS + (wave * 16 + j * 8) * BK], asrc[j] + k0);
      gload16(&Bs[buf * TILE_ELEMS + (wave * 16 + j * 8) * BK], bsrc[j] + k0);
    }
  };
  auto compute = [&](int buf) {
    const unsigned short* Ab = &As[buf * TILE_ELEMS];
    const unsigned short* Bb = &Bs[buf * TILE_ELEMS];
    bf16x8 a[2][2], b[2][2];
#pragma unroll
    for (int kk = 0; kk < 2; kk++) {
      const int xch = ((kk * 4 + (lane >> 4)) ^ (lane & 7)) * 8;
#pragma unroll
      for (int mi = 0; mi < 2; mi++)
        a[kk][mi] = *(const bf16x8*)&Ab[(wr * 32 + mi * 16 + fr) * BK + xch];
#pragma unroll
      for (int nj = 0; nj < 2; nj++)
        b[kk][nj] = *(const bf16x8*)&Bb[(wc * 32 + nj * 16 + fr) * BK + xch];
    }
#pragma unroll
    for (int kk = 0; kk < 2; kk++)
#pragma unroll
      for (int mi = 0; mi < 2; mi++)
#pragma unroll
        for (int nj = 0; nj < 2; nj++)
          acc[mi][nj] = __builtin_amdgcn_mfma_f32_16x16x32_bf16(a[kk][mi], b[kk][nj], acc[mi][nj], 0, 0, 0);
  };

  stage(0, 0);
  __syncthreads();
  int cur = 0;
  const int NT = (F_ / 2) / BK;   // 16
  for (int t = 0; t < NT - 1; t++) {
    stage(cur ^ 1, (t + 1) * BK);
    compute(cur);
    __syncthreads();
    cur ^= 1;
  }
  compute(cur);

  const int lr = (lane >> 4) * 4;
#pragma unroll
  for (int mi = 0; mi < 2; mi++) {
#pragma unroll
    for (int rg = 0; rg < 4; rg++) {
      const int row = m0 + wr * 32 + mi * 16 + lr + rg;
      const int tok = sel[e * ROWS + row];
      const float g = gate[e * ROWS + row];
#pragma unroll
      for (int nj = 0; nj < 2; nj++) {
        const int col = n0 + wc * 32 + nj * 16 + fr;
        float v = acc[mi][nj][rg];
        if (khalf == 0) v += b2[e * O_ + col];
        atomicAdd(&out[(size_t)tok * O_ + col], g * v);
      }
    }
  }
}

// ---------- launch ----------
extern "C" void kernel_launch(void* const* d_in, const int* in_sizes, int n_in,
                              void* d_out, int out_size, void* d_ws, size_t ws_size,
                              hipStream_t stream) {
  const float* x     = (const float*)d_in[0];
  const float* wg    = (const float*)d_in[1];
  const float* w1    = (const float*)d_in[2];
  const float* b1    = (const float*)d_in[3];
  const float* g_ln  = (const float*)d_in[4];
  const float* b_ln  = (const float*)d_in[5];
  const float* w2    = (const float*)d_in[6];
  const float* b2    = (const float*)d_in[7];
  float* out = (float*)d_out;
  float* out_logits = out + (size_t)NTOK * O_;

  char* wsb = (char*)d_ws;
  unsigned short* xb   = (unsigned short*)(wsb + 0);          // 8,388,608 B
  unsigned short* w1t  = (unsigned short*)(wsb + 8388608);    // 33,554,432 B
  unsigned short* w2t  = (unsigned short*)(wsb + 41943040);   // 33,554,432 B
  unsigned short* hbuf = (unsigned short*)(wsb + 75497472);   // 16,777,216 B
  float* probs = (float*)(wsb + 92274688);                    // 131,072 B
  int*   sel   = (int*)  (wsb + 92405760);                    // 16,384 B
  float* gate  = (float*)(wsb + 92422144);                    // 16,384 B

  // zero the moe-output region (atomic accumulation target)
  hipMemsetAsync(d_out, 0, (size_t)NTOK * O_ * sizeof(float), stream);

  gating_kernel<<<NTOK / 4, 256, 0, stream>>>(x, wg, out_logits, probs, xb);
  transpose_cvt_kernel<<<dim3(F_ / 64, D_ / 64, E_), 256, 0, stream>>>(w1, w1t, D_, F_); // -> [F][D]
  transpose_cvt_kernel<<<dim3(O_ / 64, F_ / 64, E_), 256, 0, stream>>>(w2, w2t, F_, O_); // -> [O][F]
  topk_kernel<<<2 * E_ * 8, 256, 0, stream>>>(out_logits, probs, sel, gate);

  // dark A/B: hybrid gemm1 (output fully overwritten by canonical gemm1)
  gemm1_hyb_kernel<<<1024, 256, 0, stream>>>(xb, w1t, b1, sel, hbuf);

  gemm1_kernel<<<(F_ / BN) * (ROWS / BM) * E_, 256, 0, stream>>>(xb, w1t, b1, sel, hbuf);
  ln_kernel<<<E_ * ROWS, 256, 0, stream>>>(hbuf, g_ln, b_ln);
  gemm2_kernel<<<2048, 256, 0, stream>>>(hbuf, w2t, b2, sel, gate, out);
}

// Round 9
// 186.946 us; speedup vs baseline: 1.1464x; 1.1464x over previous
//
#include <hip/hip_runtime.h>
#include <cstdint>
#include <cstddef>

typedef __attribute__((ext_vector_type(8))) short bf16x8;
typedef __attribute__((ext_vector_type(4))) float f32x4;

#define S_    2048
#define D_    1024
#define F_    2048
#define O_    1024
#define E_    8
#define KCAP  256
#define ROWS  512           // 2 batches * KCAP per expert
#define NTOK  4096          // B*S

#define BM 64
#define BN 64
#define BK 64
#define TILE_ELEMS (BM * BK)

// ---------- bf16 helpers ----------
__device__ __forceinline__ unsigned short f2bf(float f) {
  unsigned int u = __float_as_uint(f);
  u = (u + 0x7fffu + ((u >> 16) & 1u)) >> 16;   // RNE
  return (unsigned short)u;
}
__device__ __forceinline__ float bf2f(unsigned short h) {
  return __uint_as_float(((unsigned int)h) << 16);
}

// ---------- async global->LDS, 16B per lane, wave-uniform LDS base ----------
__device__ __forceinline__ void gload16(void* lds, const void* g) {
  auto gp = (__attribute__((address_space(1))) unsigned int*)(uintptr_t)g;
  auto lp = (__attribute__((address_space(3))) unsigned int*)(unsigned int)(uintptr_t)lds;
  __builtin_amdgcn_global_load_lds(gp, lp, 16, 0, 0);
}

// ---------- gating: logits (fp64 accum) + softmax probs + x->bf16 ----------
__global__ void gating_kernel(const float* __restrict__ x, const float* __restrict__ wg,
                              float* __restrict__ logits, float* __restrict__ probs,
                              unsigned short* __restrict__ xb) {
  const int wave = threadIdx.x >> 6, lane = threadIdx.x & 63;
  const int t = blockIdx.x * 4 + wave;
  const float* xr = x + (size_t)t * D_;
  double acc[8] = {0, 0, 0, 0, 0, 0, 0, 0};
  const int d0 = lane * 16;
#pragma unroll
  for (int i = 0; i < 4; i++) {
    float4 xv = *(const float4*)&xr[d0 + i * 4];
    union { ushort4 u4; unsigned short u[4]; } cv;
    cv.u[0] = f2bf(xv.x); cv.u[1] = f2bf(xv.y); cv.u[2] = f2bf(xv.z); cv.u[3] = f2bf(xv.w);
    *(ushort4*)&xb[(size_t)t * D_ + d0 + i * 4] = cv.u4;
    float xs[4] = {xv.x, xv.y, xv.z, xv.w};
#pragma unroll
    for (int j = 0; j < 4; j++) {
      const float4* wr = (const float4*)&wg[(size_t)(d0 + i * 4 + j) * 8];
      float4 w0 = wr[0], w1v = wr[1];
      double xd = (double)xs[j];
      acc[0] += xd * (double)w0.x;  acc[1] += xd * (double)w0.y;
      acc[2] += xd * (double)w0.z;  acc[3] += xd * (double)w0.w;
      acc[4] += xd * (double)w1v.x; acc[5] += xd * (double)w1v.y;
      acc[6] += xd * (double)w1v.z; acc[7] += xd * (double)w1v.w;
    }
  }
#pragma unroll
  for (int off = 32; off; off >>= 1) {
#pragma unroll
    for (int e = 0; e < 8; e++) acc[e] += __shfl_down(acc[e], off);
  }
  if (lane == 0) {
    double m = acc[0];
    for (int e = 1; e < 8; e++) m = acc[e] > m ? acc[e] : m;
    double p[8]; double s = 0;
    for (int e = 0; e < 8; e++) { p[e] = exp(acc[e] - m); s += p[e]; }
    const double inv = 1.0 / s;
    for (int e = 0; e < 8; e++) {
      logits[(size_t)t * 8 + e] = (float)acc[e];
      probs [(size_t)t * 8 + e] = (float)(p[e] * inv);
    }
  }
}

// ---------- per-expert transpose + fp32->bf16: out[C][R] = in[R][C] ----------
__global__ void transpose_cvt_kernel(const float* __restrict__ in, unsigned short* __restrict__ out,
                                     const int R, const int C) {
  __shared__ float t[64][65];
  const int e = blockIdx.z;
  const float* inp = in + (size_t)e * R * C;
  unsigned short* outp = out + (size_t)e * R * C;
  const int r0 = blockIdx.y * 64, c0 = blockIdx.x * 64;
  const int tid = threadIdx.x;
  const int lr = tid >> 4;          // 0..15
  const int lc = (tid & 15) * 4;    // 0..60
#pragma unroll
  for (int i = 0; i < 4; i++) {
    const int r = lr + i * 16;
    const float4 v = *(const float4*)&inp[(size_t)(r0 + r) * C + c0 + lc];
    t[r][lc] = v.x; t[r][lc + 1] = v.y; t[r][lc + 2] = v.z; t[r][lc + 3] = v.w;
  }
  __syncthreads();
#pragma unroll
  for (int i = 0; i < 4; i++) {
    const int oc = lr + i * 16;     // output row (a C-index)
    union { ushort4 u4; unsigned short u[4]; } u;
#pragma unroll
    for (int j = 0; j < 4; j++) u.u[j] = f2bf(t[lc + j][oc]);
    *(ushort4*)&outp[(size_t)(c0 + oc) * R + r0 + lc] = u.u4;
  }
}

// ---------- expert-choice top-k: u32-key rank counting, 3-region loop ----------
__global__ void topk_kernel(const float* __restrict__ logits, const float* __restrict__ probs,
                            int* __restrict__ sel, float* __restrict__ gate) {
  __shared__ unsigned int keys[S_];
  const int idx = blockIdx.x;       // 0..127 : (b,e) x 8 segments
  const int seg = idx & 7;
  const int be = idx >> 3;          // 0..15
  const int b = be >> 3;            // 0..1
  const int e = be & 7;
  const int tid = threadIdx.x;
  for (int i = tid; i < S_; i += 256) {
    unsigned int u = __float_as_uint(logits[((size_t)(b * S_ + i)) * E_ + e]);
    keys[i] = u ^ ((u & 0x80000000u) ? 0xFFFFFFFFu : 0x80000000u);
  }
  __syncthreads();
  const int s = seg * 256 + tid;
  const unsigned int vk = keys[s];
  const int wave = tid >> 6;
  const int W0 = seg * 256 + wave * 64;
  int rank = 0;
#pragma unroll 4
  for (int i = 0; i < W0; i += 4) {
    const uint4 kv = *(const uint4*)&keys[i];
    rank += (kv.x >= vk) + (kv.y >= vk) + (kv.z >= vk) + (kv.w >= vk);
  }
#pragma unroll
  for (int j = 0; j < 64; j++) {
    const int i = W0 + j;
    const unsigned int kv = keys[i];
    rank += (kv > vk) || (kv == vk && i < s);
  }
#pragma unroll 4
  for (int i = W0 + 64; i < S_; i += 4) {
    const uint4 kv = *(const uint4*)&keys[i];
    rank += (kv.x > vk) + (kv.y > vk) + (kv.z > vk) + (kv.w > vk);
  }
  if (rank < KCAP) {
    sel [e * ROWS + b * KCAP + rank] = b * S_ + s;
    gate[e * ROWS + b * KCAP + rank] = probs[((size_t)(b * S_ + s)) * E_ + e];
  }
}

// ====================== DARK D1: gemm1 single-buffer 16KB LDS, 8 blocks/CU ======================
// Mechanism under test: inter-block TLP (32 waves/CU) covers the stage stall
// better than intra-block double-buffering (R3: 5 blocks/CU, 20 waves).
__global__ __launch_bounds__(256, 8) void gemm1_sb_kernel(
    const unsigned short* __restrict__ xb, const unsigned short* __restrict__ w1t,
    const float* __restrict__ b1, const int* __restrict__ sel,
    unsigned short* __restrict__ hbuf) {
  __shared__ unsigned short As[TILE_ELEMS];   // 8 KB
  __shared__ unsigned short Bs[TILE_ELEMS];   // 8 KB
  const int bid = blockIdx.x;
  const int lid = (bid & 7) * 256 + (bid >> 3);
  const int e   = lid >> 8;
  const int rem = lid & 255;
  const int n0  = (rem >> 3) * BN;
  const int m0  = (rem & 7) * BM;
  const int tid = threadIdx.x;
  const int wave = tid >> 6, lane = tid & 63;
  const int wr = wave >> 1, wc = wave & 1;

  const int srow = lane >> 3;
  const int schunk = (lane & 7) ^ srow;
  const unsigned short* asrc[2];
  const unsigned short* bsrc[2];
#pragma unroll
  for (int j = 0; j < 2; j++) {
    const int r = wave * 16 + j * 8 + srow;
    const int tok = sel[e * ROWS + m0 + r];
    asrc[j] = xb + (size_t)tok * D_ + schunk * 8;
    bsrc[j] = w1t + ((size_t)e * F_ + n0 + r) * D_ + schunk * 8;
  }

  f32x4 acc[2][2];
#pragma unroll
  for (int mi = 0; mi < 2; mi++)
#pragma unroll
    for (int nj = 0; nj < 2; nj++) acc[mi][nj] = (f32x4){0.f, 0.f, 0.f, 0.f};

  const int fr = lane & 15;

  for (int t = 0; t < D_ / BK; t++) {
    const int k0 = t * BK;
#pragma unroll
    for (int j = 0; j < 2; j++) {
      gload16(&As[(wave * 16 + j * 8) * BK], asrc[j] + k0);
      gload16(&Bs[(wave * 16 + j * 8) * BK], bsrc[j] + k0);
    }
    __syncthreads();                 // staging complete (implicit vmcnt(0))
    bf16x8 a[2][2], b[2][2];
#pragma unroll
    for (int kk = 0; kk < 2; kk++) {
      const int xch = ((kk * 4 + (lane >> 4)) ^ (lane & 7)) * 8;
#pragma unroll
      for (int mi = 0; mi < 2; mi++)
        a[kk][mi] = *(const bf16x8*)&As[(wr * 32 + mi * 16 + fr) * BK + xch];
#pragma unroll
      for (int nj = 0; nj < 2; nj++)
        b[kk][nj] = *(const bf16x8*)&Bs[(wc * 32 + nj * 16 + fr) * BK + xch];
    }
#pragma unroll
    for (int kk = 0; kk < 2; kk++)
#pragma unroll
      for (int mi = 0; mi < 2; mi++)
#pragma unroll
        for (int nj = 0; nj < 2; nj++)
          acc[mi][nj] = __builtin_amdgcn_mfma_f32_16x16x32_bf16(a[kk][mi], b[kk][nj], acc[mi][nj], 0, 0, 0);
    __syncthreads();                 // all waves done reading before next overwrite
  }

  const int lr = (lane >> 4) * 4;
#pragma unroll
  for (int mi = 0; mi < 2; mi++)
#pragma unroll
    for (int nj = 0; nj < 2; nj++)
#pragma unroll
      for (int rg = 0; rg < 4; rg++) {
        const int row = m0 + wr * 32 + mi * 16 + lr + rg;
        const int col = n0 + wc * 32 + nj * 16 + fr;
        float v = acc[mi][nj][rg] + b1[e * F_ + col];
        v = 0.5f * v * (1.0f + erff(v * 0.70710678118654752f));
        hbuf[((size_t)e * ROWS + row) * F_ + col] = f2bf(v);
      }
}

// ====================== CANONICAL GEMM1 (R3, proven 46us) ======================
__global__ __launch_bounds__(256, 4) void gemm1_kernel(
    const unsigned short* __restrict__ xb,   // [NTOK][D_]
    const unsigned short* __restrict__ w1t,  // [E][F_][D_]
    const float* __restrict__ b1,            // [E][F_]
    const int* __restrict__ sel,             // [E][ROWS]
    unsigned short* __restrict__ hbuf) {     // [E][ROWS][F_]
  __shared__ unsigned short As[2 * TILE_ELEMS];
  __shared__ unsigned short Bs[2 * TILE_ELEMS];
  const int bid = blockIdx.x;
  const int lid = (bid & 7) * 256 + (bid >> 3);
  const int e   = lid >> 8;
  const int rem = lid & 255;
  const int n0  = (rem >> 3) * BN;
  const int m0  = (rem & 7) * BM;
  const int tid = threadIdx.x;
  const int wave = tid >> 6, lane = tid & 63;
  const int wr = wave >> 1, wc = wave & 1;

  const int srow = lane >> 3;
  const int schunk = (lane & 7) ^ srow;
  const unsigned short* asrc[2];
  const unsigned short* bsrc[2];
#pragma unroll
  for (int j = 0; j < 2; j++) {
    const int r = wave * 16 + j * 8 + srow;
    const int tok = sel[e * ROWS + m0 + r];
    asrc[j] = xb + (size_t)tok * D_ + schunk * 8;
    bsrc[j] = w1t + ((size_t)e * F_ + n0 + r) * D_ + schunk * 8;
  }

  f32x4 acc[2][2];
#pragma unroll
  for (int mi = 0; mi < 2; mi++)
#pragma unroll
    for (int nj = 0; nj < 2; nj++) acc[mi][nj] = (f32x4){0.f, 0.f, 0.f, 0.f};

  const int fr = lane & 15;

  auto stage = [&](int buf, int k0) {
#pragma unroll
    for (int j = 0; j < 2; j++) {
      gload16(&As[buf * TILE_ELEMS + (wave * 16 + j * 8) * BK], asrc[j] + k0);
      gload16(&Bs[buf * TILE_ELEMS + (wave * 16 + j * 8) * BK], bsrc[j] + k0);
    }
  };
  auto compute = [&](int buf) {
    const unsigned short* Ab = &As[buf * TILE_ELEMS];
    const unsigned short* Bb = &Bs[buf * TILE_ELEMS];
    bf16x8 a[2][2], b[2][2];
#pragma unroll
    for (int kk = 0; kk < 2; kk++) {
      const int xch = ((kk * 4 + (lane >> 4)) ^ (lane & 7)) * 8;
#pragma unroll
      for (int mi = 0; mi < 2; mi++)
        a[kk][mi] = *(const bf16x8*)&Ab[(wr * 32 + mi * 16 + fr) * BK + xch];
#pragma unroll
      for (int nj = 0; nj < 2; nj++)
        b[kk][nj] = *(const bf16x8*)&Bb[(wc * 32 + nj * 16 + fr) * BK + xch];
    }
#pragma unroll
    for (int kk = 0; kk < 2; kk++)
#pragma unroll
      for (int mi = 0; mi < 2; mi++)
#pragma unroll
        for (int nj = 0; nj < 2; nj++)
          acc[mi][nj] = __builtin_amdgcn_mfma_f32_16x16x32_bf16(a[kk][mi], b[kk][nj], acc[mi][nj], 0, 0, 0);
  };

  stage(0, 0);
  __syncthreads();
  int cur = 0;
  for (int t = 0; t < D_ / BK - 1; t++) {
    stage(cur ^ 1, (t + 1) * BK);
    compute(cur);
    __syncthreads();
    cur ^= 1;
  }
  compute(cur);

  const int lr = (lane >> 4) * 4;
#pragma unroll
  for (int mi = 0; mi < 2; mi++)
#pragma unroll
    for (int nj = 0; nj < 2; nj++)
#pragma unroll
      for (int rg = 0; rg < 4; rg++) {
        const int row = m0 + wr * 32 + mi * 16 + lr + rg;
        const int col = n0 + wc * 32 + nj * 16 + fr;
        float v = acc[mi][nj][rg] + b1[e * F_ + col];
        v = 0.5f * v * (1.0f + erff(v * 0.70710678118654752f));   // exact GELU
        hbuf[((size_t)e * ROWS + row) * F_ + col] = f2bf(v);
      }
}

// ---------- row LayerNorm over F_, in place on bf16 h ----------
__global__ void ln_kernel(unsigned short* __restrict__ hbuf,
                          const float* __restrict__ g_ln, const float* __restrict__ b_ln) {
  const int row = blockIdx.x;          // 0..E_*ROWS-1
  const int e = row >> 9;
  unsigned short* hr = hbuf + (size_t)row * F_;
  const int tid = threadIdx.x;
  union { bf16x8 v; unsigned short u[8]; } u;
  u.v = *(const bf16x8*)&hr[tid * 8];
  float vals[8]; float s1 = 0.f, s2 = 0.f;
#pragma unroll
  for (int j = 0; j < 8; j++) { float f = bf2f(u.u[j]); vals[j] = f; s1 += f; s2 += f * f; }
#pragma unroll
  for (int off = 32; off; off >>= 1) { s1 += __shfl_down(s1, off); s2 += __shfl_down(s2, off); }
  __shared__ float rs[8];
  const int wave = tid >> 6, lane = tid & 63;
  if (lane == 0) { rs[wave] = s1; rs[wave + 4] = s2; }
  __syncthreads();
  const float t1 = rs[0] + rs[1] + rs[2] + rs[3];
  const float t2 = rs[4] + rs[5] + rs[6] + rs[7];
  const float mu = t1 * (1.f / F_);
  const float var = t2 * (1.f / F_) - mu * mu;   // biased var (jnp.var)
  const float rstd = rsqrtf(var + 1e-5f);
  const float4* gl4 = (const float4*)(g_ln + (size_t)e * F_ + tid * 8);
  const float4* bl4 = (const float4*)(b_ln + (size_t)e * F_ + tid * 8);
  float4 g0 = gl4[0], g1 = gl4[1], bb0 = bl4[0], bb1 = bl4[1];
  float gs[8] = {g0.x, g0.y, g0.z, g0.w, g1.x, g1.y, g1.z, g1.w};
  float bs[8] = {bb0.x, bb0.y, bb0.z, bb0.w, bb1.x, bb1.y, bb1.z, bb1.w};
  union { bf16x8 v; unsigned short u[8]; } o;
#pragma unroll
  for (int j = 0; j < 8; j++)
    o.u[j] = f2bf((vals[j] - mu) * rstd * gs[j] + bs[j]);
  *(bf16x8*)&hr[tid * 8] = o.v;
}

// ====================== GEMM2 (R3, proven): out[tok] += gate * (h . w2^T + b2) ======================
__global__ __launch_bounds__(256, 4) void gemm2_kernel(
    const unsigned short* __restrict__ hbuf, // [E][ROWS][F_]
    const unsigned short* __restrict__ w2t,  // [E][O_][F_]
    const float* __restrict__ b2,            // [E][O_]
    const int* __restrict__ sel, const float* __restrict__ gate,
    float* __restrict__ out) {               // [NTOK][O_]
  __shared__ unsigned short As[2 * TILE_ELEMS];
  __shared__ unsigned short Bs[2 * TILE_ELEMS];
  const int bid = blockIdx.x;
  const int lid = (bid & 7) * 128 + (bid >> 3);
  const int e   = lid >> 7;
  const int rem = lid & 127;
  const int n0  = (rem >> 3) * BN;
  const int m0  = (rem & 7) * BM;
  const int tid = threadIdx.x;
  const int wave = tid >> 6, lane = tid & 63;
  const int wr = wave >> 1, wc = wave & 1;

  const int srow = lane >> 3;
  const int schunk = (lane & 7) ^ srow;
  const unsigned short* asrc[2];
  const unsigned short* bsrc[2];
#pragma unroll
  for (int j = 0; j < 2; j++) {
    const int r = wave * 16 + j * 8 + srow;
    asrc[j] = hbuf + ((size_t)e * ROWS + m0 + r) * F_ + schunk * 8;
    bsrc[j] = w2t + ((size_t)e * O_ + n0 + r) * F_ + schunk * 8;
  }

  f32x4 acc[2][2];
#pragma unroll
  for (int mi = 0; mi < 2; mi++)
#pragma unroll
    for (int nj = 0; nj < 2; nj++) acc[mi][nj] = (f32x4){0.f, 0.f, 0.f, 0.f};

  const int fr = lane & 15;

  auto stage = [&](int buf, int k0) {
#pragma unroll
    for (int j = 0; j < 2; j++) {
      gload16(&As[buf * TILE_ELEMS + (wave * 16 + j * 8) * BK], asrc[j] + k0);
      gload16(&Bs[buf * TILE_ELEMS + (wave * 16 + j * 8) * BK], bsrc[j] + k0);
    }
  };
  auto compute = [&](int buf) {
    const unsigned short* Ab = &As[buf * TILE_ELEMS];
    const unsigned short* Bb = &Bs[buf * TILE_ELEMS];
    bf16x8 a[2][2], b[2][2];
#pragma unroll
    for (int kk = 0; kk < 2; kk++) {
      const int xch = ((kk * 4 + (lane >> 4)) ^ (lane & 7)) * 8;
#pragma unroll
      for (int mi = 0; mi < 2; mi++)
        a[kk][mi] = *(const bf16x8*)&Ab[(wr * 32 + mi * 16 + fr) * BK + xch];
#pragma unroll
      for (int nj = 0; nj < 2; nj++)
        b[kk][nj] = *(const bf16x8*)&Bb[(wc * 32 + nj * 16 + fr) * BK + xch];
    }
#pragma unroll
    for (int kk = 0; kk < 2; kk++)
#pragma unroll
      for (int mi = 0; mi < 2; mi++)
#pragma unroll
        for (int nj = 0; nj < 2; nj++)
          acc[mi][nj] = __builtin_amdgcn_mfma_f32_16x16x32_bf16(a[kk][mi], b[kk][nj], acc[mi][nj], 0, 0, 0);
  };

  stage(0, 0);
  __syncthreads();
  int cur = 0;
  for (int t = 0; t < F_ / BK - 1; t++) {
    stage(cur ^ 1, (t + 1) * BK);
    compute(cur);
    __syncthreads();
    cur ^= 1;
  }
  compute(cur);

  const int lr = (lane >> 4) * 4;
#pragma unroll
  for (int mi = 0; mi < 2; mi++) {
#pragma unroll
    for (int rg = 0; rg < 4; rg++) {
      const int row = m0 + wr * 32 + mi * 16 + lr + rg;
      const int tok = sel[e * ROWS + row];
      const float g = gate[e * ROWS + row];
#pragma unroll
      for (int nj = 0; nj < 2; nj++) {
        const int col = n0 + wc * 32 + nj * 16 + fr;
        const float v = acc[mi][nj][rg] + b2[e * O_ + col];
        atomicAdd(&out[(size_t)tok * O_ + col], g * v);
      }
    }
  }
}

// ---------- launch ----------
extern "C" void kernel_launch(void* const* d_in, const int* in_sizes, int n_in,
                              void* d_out, int out_size, void* d_ws, size_t ws_size,
                              hipStream_t stream) {
  const float* x     = (const float*)d_in[0];
  const float* wg    = (const float*)d_in[1];
  const float* w1    = (const float*)d_in[2];
  const float* b1    = (const float*)d_in[3];
  const float* g_ln  = (const float*)d_in[4];
  const float* b_ln  = (const float*)d_in[5];
  const float* w2    = (const float*)d_in[6];
  const float* b2    = (const float*)d_in[7];
  float* out = (float*)d_out;
  float* out_logits = out + (size_t)NTOK * O_;

  char* wsb = (char*)d_ws;
  unsigned short* xb   = (unsigned short*)(wsb + 0);          // 8,388,608 B
  unsigned short* w1t  = (unsigned short*)(wsb + 8388608);    // 33,554,432 B
  unsigned short* w2t  = (unsigned short*)(wsb + 41943040);   // 33,554,432 B
  unsigned short* hbuf = (unsigned short*)(wsb + 75497472);   // 16,777,216 B
  float* probs = (float*)(wsb + 92274688);                    // 131,072 B
  int*   sel   = (int*)  (wsb + 92405760);                    // 16,384 B
  float* gate  = (float*)(wsb + 92422144);                    // 16,384 B

  // zero the moe-output region (atomic accumulation target)
  hipMemsetAsync(d_out, 0, (size_t)NTOK * O_ * sizeof(float), stream);

  gating_kernel<<<NTOK / 4, 256, 0, stream>>>(x, wg, out_logits, probs, xb);
  transpose_cvt_kernel<<<dim3(F_ / 64, D_ / 64, E_), 256, 0, stream>>>(w1, w1t, D_, F_); // -> [F][D]
  transpose_cvt_kernel<<<dim3(O_ / 64, F_ / 64, E_), 256, 0, stream>>>(w2, w2t, F_, O_); // -> [O][F]
  topk_kernel<<<2 * E_ * 8, 256, 0, stream>>>(out_logits, probs, sel, gate);

  // dark A/B probe: single-buffer high-TLP gemm1 (output overwritten by canonical)
  gemm1_sb_kernel<<<(F_ / BN) * (ROWS / BM) * E_, 256, 0, stream>>>(xb, w1t, b1, sel, hbuf);

  gemm1_kernel<<<(F_ / BN) * (ROWS / BM) * E_, 256, 0, stream>>>(xb, w1t, b1, sel, hbuf);
  ln_kernel<<<E_ * ROWS, 256, 0, stream>>>(hbuf, g_ln, b_ln);
  gemm2_kernel<<<(O_ / BN) * (ROWS / BM) * E_, 256, 0, stream>>>(hbuf, w2t, b2, sel, gate, out);
}

// Round 10
// 155.395 us; speedup vs baseline: 1.3791x; 1.2030x over previous
//
#include <hip/hip_runtime.h>
#include <cstdint>
#include <cstddef>

typedef __attribute__((ext_vector_type(8))) short bf16x8;
typedef __attribute__((ext_vector_type(4))) float f32x4;

#define S_    2048
#define D_    1024
#define F_    2048
#define O_    1024
#define E_    8
#define KCAP  256
#define ROWS  512           // 2 batches * KCAP per expert
#define NTOK  4096          // B*S

#define BM 64
#define BN 64
#define BK 64
#define TILE_ELEMS (BM * BK)

// ---------- bf16 helpers ----------
__device__ __forceinline__ unsigned short f2bf(float f) {
  unsigned int u = __float_as_uint(f);
  u = (u + 0x7fffu + ((u >> 16) & 1u)) >> 16;   // RNE
  return (unsigned short)u;
}
__device__ __forceinline__ float bf2f(unsigned short h) {
  return __uint_as_float(((unsigned int)h) << 16);
}

// ---------- async global->LDS, 16B per lane, wave-uniform LDS base ----------
__device__ __forceinline__ void gload16(void* lds, const void* g) {
  auto gp = (__attribute__((address_space(1))) unsigned int*)(uintptr_t)g;
  auto lp = (__attribute__((address_space(3))) unsigned int*)(unsigned int)(uintptr_t)lds;
  __builtin_amdgcn_global_load_lds(gp, lp, 16, 0, 0);
}

// ---------- gating: logits (fp64 accum) + softmax probs + x->bf16 ----------
__global__ void gating_kernel(const float* __restrict__ x, const float* __restrict__ wg,
                              float* __restrict__ logits, float* __restrict__ probs,
                              unsigned short* __restrict__ xb) {
  const int wave = threadIdx.x >> 6, lane = threadIdx.x & 63;
  const int t = blockIdx.x * 4 + wave;
  const float* xr = x + (size_t)t * D_;
  double acc[8] = {0, 0, 0, 0, 0, 0, 0, 0};
  const int d0 = lane * 16;
#pragma unroll
  for (int i = 0; i < 4; i++) {
    float4 xv = *(const float4*)&xr[d0 + i * 4];
    union { ushort4 u4; unsigned short u[4]; } cv;
    cv.u[0] = f2bf(xv.x); cv.u[1] = f2bf(xv.y); cv.u[2] = f2bf(xv.z); cv.u[3] = f2bf(xv.w);
    *(ushort4*)&xb[(size_t)t * D_ + d0 + i * 4] = cv.u4;
    float xs[4] = {xv.x, xv.y, xv.z, xv.w};
#pragma unroll
    for (int j = 0; j < 4; j++) {
      const float4* wr = (const float4*)&wg[(size_t)(d0 + i * 4 + j) * 8];
      float4 w0 = wr[0], w1v = wr[1];
      double xd = (double)xs[j];
      acc[0] += xd * (double)w0.x;  acc[1] += xd * (double)w0.y;
      acc[2] += xd * (double)w0.z;  acc[3] += xd * (double)w0.w;
      acc[4] += xd * (double)w1v.x; acc[5] += xd * (double)w1v.y;
      acc[6] += xd * (double)w1v.z; acc[7] += xd * (double)w1v.w;
    }
  }
#pragma unroll
  for (int off = 32; off; off >>= 1) {
#pragma unroll
    for (int e = 0; e < 8; e++) acc[e] += __shfl_down(acc[e], off);
  }
  if (lane == 0) {
    double m = acc[0];
    for (int e = 1; e < 8; e++) m = acc[e] > m ? acc[e] : m;
    double p[8]; double s = 0;
    for (int e = 0; e < 8; e++) { p[e] = exp(acc[e] - m); s += p[e]; }
    const double inv = 1.0 / s;
    for (int e = 0; e < 8; e++) {
      logits[(size_t)t * 8 + e] = (float)acc[e];
      probs [(size_t)t * 8 + e] = (float)(p[e] * inv);
    }
  }
}

// ---------- per-expert transpose + fp32->bf16: out[C][R] = in[R][C] ----------
__global__ void transpose_cvt_kernel(const float* __restrict__ in, unsigned short* __restrict__ out,
                                     const int R, const int C) {
  __shared__ float t[64][65];
  const int e = blockIdx.z;
  const float* inp = in + (size_t)e * R * C;
  unsigned short* outp = out + (size_t)e * R * C;
  const int r0 = blockIdx.y * 64, c0 = blockIdx.x * 64;
  const int tid = threadIdx.x;
  const int lr = tid >> 4;          // 0..15
  const int lc = (tid & 15) * 4;    // 0..60
#pragma unroll
  for (int i = 0; i < 4; i++) {
    const int r = lr + i * 16;
    const float4 v = *(const float4*)&inp[(size_t)(r0 + r) * C + c0 + lc];
    t[r][lc] = v.x; t[r][lc + 1] = v.y; t[r][lc + 2] = v.z; t[r][lc + 3] = v.w;
  }
  __syncthreads();
#pragma unroll
  for (int i = 0; i < 4; i++) {
    const int oc = lr + i * 16;     // output row (a C-index)
    union { ushort4 u4; unsigned short u[4]; } u;
#pragma unroll
    for (int j = 0; j < 4; j++) u.u[j] = f2bf(t[lc + j][oc]);
    *(ushort4*)&outp[(size_t)(c0 + oc) * R + r0 + lc] = u.u4;
  }
}

// ---------- expert-choice top-k + deterministic per-token inverse index ----------
__global__ void topk_kernel(const float* __restrict__ logits, const float* __restrict__ probs,
                            int* __restrict__ sel, float* __restrict__ gate,
                            int* __restrict__ entry) {    // entry[tok][e] = row+1 (0 = absent)
  __shared__ unsigned int keys[S_];
  const int idx = blockIdx.x;       // 0..127 : (b,e) x 8 segments
  const int seg = idx & 7;
  const int be = idx >> 3;          // 0..15
  const int b = be >> 3;            // 0..1
  const int e = be & 7;
  const int tid = threadIdx.x;
  for (int i = tid; i < S_; i += 256) {
    unsigned int u = __float_as_uint(logits[((size_t)(b * S_ + i)) * E_ + e]);
    keys[i] = u ^ ((u & 0x80000000u) ? 0xFFFFFFFFu : 0x80000000u);
  }
  __syncthreads();
  const int s = seg * 256 + tid;
  const unsigned int vk = keys[s];
  const int wave = tid >> 6;
  const int W0 = seg * 256 + wave * 64;
  int rank = 0;
#pragma unroll 4
  for (int i = 0; i < W0; i += 4) {
    const uint4 kv = *(const uint4*)&keys[i];
    rank += (kv.x >= vk) + (kv.y >= vk) + (kv.z >= vk) + (kv.w >= vk);
  }
#pragma unroll
  for (int j = 0; j < 64; j++) {
    const int i = W0 + j;
    const unsigned int kv = keys[i];
    rank += (kv > vk) || (kv == vk && i < s);
  }
#pragma unroll 4
  for (int i = W0 + 64; i < S_; i += 4) {
    const uint4 kv = *(const uint4*)&keys[i];
    rank += (kv.x > vk) + (kv.y > vk) + (kv.z > vk) + (kv.w > vk);
  }
  if (rank < KCAP) {
    const int row = b * KCAP + rank;
    const int tok = b * S_ + s;
    sel  [e * ROWS + row] = tok;
    gate [e * ROWS + row] = probs[(size_t)tok * E_ + e];
    entry[tok * E_ + e]   = row + 1;        // slot-per-expert: deterministic combine order
  }
}

// ====================== GEMM1 (promoted D1): single-buffer, 8 blocks/CU ======================
// 64x64x64, 4 waves, 16KB LDS single-buffer, gload16 + XOR swizzle, expert-per-XCD.
// Inter-block TLP (32 waves/CU) covers the per-step vmcnt(0) drain.
__global__ __launch_bounds__(256, 8) void gemm1_kernel(
    const unsigned short* __restrict__ xb, const unsigned short* __restrict__ w1t,
    const float* __restrict__ b1, const int* __restrict__ sel,
    unsigned short* __restrict__ hbuf) {
  __shared__ unsigned short As[TILE_ELEMS];   // 8 KB
  __shared__ unsigned short Bs[TILE_ELEMS];   // 8 KB
  const int bid = blockIdx.x;
  const int lid = (bid & 7) * 256 + (bid >> 3);
  const int e   = lid >> 8;
  const int rem = lid & 255;
  const int n0  = (rem >> 3) * BN;
  const int m0  = (rem & 7) * BM;
  const int tid = threadIdx.x;
  const int wave = tid >> 6, lane = tid & 63;
  const int wr = wave >> 1, wc = wave & 1;

  const int srow = lane >> 3;
  const int schunk = (lane & 7) ^ srow;
  const unsigned short* asrc[2];
  const unsigned short* bsrc[2];
#pragma unroll
  for (int j = 0; j < 2; j++) {
    const int r = wave * 16 + j * 8 + srow;
    const int tok = sel[e * ROWS + m0 + r];
    asrc[j] = xb + (size_t)tok * D_ + schunk * 8;
    bsrc[j] = w1t + ((size_t)e * F_ + n0 + r) * D_ + schunk * 8;
  }

  f32x4 acc[2][2];
#pragma unroll
  for (int mi = 0; mi < 2; mi++)
#pragma unroll
    for (int nj = 0; nj < 2; nj++) acc[mi][nj] = (f32x4){0.f, 0.f, 0.f, 0.f};

  const int fr = lane & 15;

  for (int t = 0; t < D_ / BK; t++) {
    const int k0 = t * BK;
#pragma unroll
    for (int j = 0; j < 2; j++) {
      gload16(&As[(wave * 16 + j * 8) * BK], asrc[j] + k0);
      gload16(&Bs[(wave * 16 + j * 8) * BK], bsrc[j] + k0);
    }
    __syncthreads();                 // staging complete (implicit vmcnt(0))
    bf16x8 a[2][2], b[2][2];
#pragma unroll
    for (int kk = 0; kk < 2; kk++) {
      const int xch = ((kk * 4 + (lane >> 4)) ^ (lane & 7)) * 8;
#pragma unroll
      for (int mi = 0; mi < 2; mi++)
        a[kk][mi] = *(const bf16x8*)&As[(wr * 32 + mi * 16 + fr) * BK + xch];
#pragma unroll
      for (int nj = 0; nj < 2; nj++)
        b[kk][nj] = *(const bf16x8*)&Bs[(wc * 32 + nj * 16 + fr) * BK + xch];
    }
#pragma unroll
    for (int kk = 0; kk < 2; kk++)
#pragma unroll
      for (int mi = 0; mi < 2; mi++)
#pragma unroll
        for (int nj = 0; nj < 2; nj++)
          acc[mi][nj] = __builtin_amdgcn_mfma_f32_16x16x32_bf16(a[kk][mi], b[kk][nj], acc[mi][nj], 0, 0, 0);
    __syncthreads();                 // all waves done reading before next overwrite
  }

  const int lr = (lane >> 4) * 4;
#pragma unroll
  for (int mi = 0; mi < 2; mi++)
#pragma unroll
    for (int nj = 0; nj < 2; nj++)
#pragma unroll
      for (int rg = 0; rg < 4; rg++) {
        const int row = m0 + wr * 32 + mi * 16 + lr + rg;
        const int col = n0 + wc * 32 + nj * 16 + fr;
        float v = acc[mi][nj][rg] + b1[e * F_ + col];
        v = 0.5f * v * (1.0f + erff(v * 0.70710678118654752f));   // exact GELU
        hbuf[((size_t)e * ROWS + row) * F_ + col] = f2bf(v);
      }
}

// ---------- row LayerNorm over F_, in place on bf16 h ----------
__global__ void ln_kernel(unsigned short* __restrict__ hbuf,
                          const float* __restrict__ g_ln, const float* __restrict__ b_ln) {
  const int row = blockIdx.x;          // 0..E_*ROWS-1
  const int e = row >> 9;
  unsigned short* hr = hbuf + (size_t)row * F_;
  const int tid = threadIdx.x;
  union { bf16x8 v; unsigned short u[8]; } u;
  u.v = *(const bf16x8*)&hr[tid * 8];
  float vals[8]; float s1 = 0.f, s2 = 0.f;
#pragma unroll
  for (int j = 0; j < 8; j++) { float f = bf2f(u.u[j]); vals[j] = f; s1 += f; s2 += f * f; }
#pragma unroll
  for (int off = 32; off; off >>= 1) { s1 += __shfl_down(s1, off); s2 += __shfl_down(s2, off); }
  __shared__ float rs[8];
  const int wave = tid >> 6, lane = tid & 63;
  if (lane == 0) { rs[wave] = s1; rs[wave + 4] = s2; }
  __syncthreads();
  const float t1 = rs[0] + rs[1] + rs[2] + rs[3];
  const float t2 = rs[4] + rs[5] + rs[6] + rs[7];
  const float mu = t1 * (1.f / F_);
  const float var = t2 * (1.f / F_) - mu * mu;   // biased var (jnp.var)
  const float rstd = rsqrtf(var + 1e-5f);
  const float4* gl4 = (const float4*)(g_ln + (size_t)e * F_ + tid * 8);
  const float4* bl4 = (const float4*)(b_ln + (size_t)e * F_ + tid * 8);
  float4 g0 = gl4[0], g1 = gl4[1], bb0 = bl4[0], bb1 = bl4[1];
  float gs[8] = {g0.x, g0.y, g0.z, g0.w, g1.x, g1.y, g1.z, g1.w};
  float bs[8] = {bb0.x, bb0.y, bb0.z, bb0.w, bb1.x, bb1.y, bb1.z, bb1.w};
  union { bf16x8 v; unsigned short u[8]; } o;
#pragma unroll
  for (int j = 0; j < 8; j++)
    o.u[j] = f2bf((vals[j] - mu) * rstd * gs[j] + bs[j]);
  *(bf16x8*)&hr[tid * 8] = o.v;
}

// ====================== GEMM2 partial: split-K x2, D1 structure, plain stores ======================
// part[khalf][e*ROWS+row][col]; 2048 blocks = 8 blocks/CU, no atomics.
__global__ __launch_bounds__(256, 8) void gemm2_partial_kernel(
    const unsigned short* __restrict__ hbuf, // [E][ROWS][F_]
    const unsigned short* __restrict__ w2t,  // [E][O_][F_]
    float* __restrict__ part) {              // [2][E_*ROWS][O_]
  __shared__ unsigned short As[TILE_ELEMS];
  __shared__ unsigned short Bs[TILE_ELEMS];
  const int bid = blockIdx.x;
  const int lid = (bid & 7) * 256 + (bid >> 3);   // 8 XCDs x 256; expert-per-XCD
  const int e     = lid >> 8;
  const int rem   = lid & 255;
  const int khalf = rem & 1;
  const int m0    = ((rem >> 1) & 7) * BM;
  const int n0    = (rem >> 4) * BN;              // 16 O panels
  const int koff  = khalf * (F_ / 2);
  const int tid = threadIdx.x;
  const int wave = tid >> 6, lane = tid & 63;
  const int wr = wave >> 1, wc = wave & 1;

  const int srow = lane >> 3;
  const int schunk = (lane & 7) ^ srow;
  const unsigned short* asrc[2];
  const unsigned short* bsrc[2];
#pragma unroll
  for (int j = 0; j < 2; j++) {
    const int r = wave * 16 + j * 8 + srow;
    asrc[j] = hbuf + ((size_t)e * ROWS + m0 + r) * F_ + koff + schunk * 8;
    bsrc[j] = w2t + ((size_t)e * O_ + n0 + r) * F_ + koff + schunk * 8;
  }

  f32x4 acc[2][2];
#pragma unroll
  for (int mi = 0; mi < 2; mi++)
#pragma unroll
    for (int nj = 0; nj < 2; nj++) acc[mi][nj] = (f32x4){0.f, 0.f, 0.f, 0.f};

  const int fr = lane & 15;

  for (int t = 0; t < (F_ / 2) / BK; t++) {   // 16 steps
    const int k0 = t * BK;
#pragma unroll
    for (int j = 0; j < 2; j++) {
      gload16(&As[(wave * 16 + j * 8) * BK], asrc[j] + k0);
      gload16(&Bs[(wave * 16 + j * 8) * BK], bsrc[j] + k0);
    }
    __syncthreads();
    bf16x8 a[2][2], b[2][2];
#pragma unroll
    for (int kk = 0; kk < 2; kk++) {
      const int xch = ((kk * 4 + (lane >> 4)) ^ (lane & 7)) * 8;
#pragma unroll
      for (int mi = 0; mi < 2; mi++)
        a[kk][mi] = *(const bf16x8*)&As[(wr * 32 + mi * 16 + fr) * BK + xch];
#pragma unroll
      for (int nj = 0; nj < 2; nj++)
        b[kk][nj] = *(const bf16x8*)&Bs[(wc * 32 + nj * 16 + fr) * BK + xch];
    }
#pragma unroll
    for (int kk = 0; kk < 2; kk++)
#pragma unroll
      for (int mi = 0; mi < 2; mi++)
#pragma unroll
        for (int nj = 0; nj < 2; nj++)
          acc[mi][nj] = __builtin_amdgcn_mfma_f32_16x16x32_bf16(a[kk][mi], b[kk][nj], acc[mi][nj], 0, 0, 0);
    __syncthreads();
  }

  float* pbase = part + (size_t)khalf * (E_ * ROWS) * O_;
  const int lr = (lane >> 4) * 4;
#pragma unroll
  for (int mi = 0; mi < 2; mi++)
#pragma unroll
    for (int rg = 0; rg < 4; rg++) {
      const int row = m0 + wr * 32 + mi * 16 + lr + rg;
#pragma unroll
      for (int nj = 0; nj < 2; nj++) {
        const int col = n0 + wc * 32 + nj * 16 + fr;
        pbase[((size_t)(e * ROWS) + row) * O_ + col] = acc[mi][nj][rg];
      }
    }
}

// ---------- combine: out[tok] = sum_e gate * (p0 + p1 + b2[e]) ; atomic-free ----------
__global__ void combine_kernel(const float* __restrict__ part, const int* __restrict__ entry,
                               const float* __restrict__ gate, const float* __restrict__ b2,
                               float* __restrict__ out) {
  const int tok = blockIdx.x;
  const int c = threadIdx.x * 4;
  float4 acc = {0.f, 0.f, 0.f, 0.f};
#pragma unroll
  for (int e = 0; e < E_; e++) {
    const int r1 = entry[tok * E_ + e];
    if (r1) {
      const int idx = e * ROWS + (r1 - 1);
      const float g = gate[idx];
      const float4 p0 = *(const float4*)&part[(size_t)idx * O_ + c];
      const float4 p1 = *(const float4*)&part[(size_t)(E_ * ROWS + idx) * O_ + c];
      const float4 bb = *(const float4*)&b2[e * O_ + c];
      acc.x += g * (p0.x + p1.x + bb.x);
      acc.y += g * (p0.y + p1.y + bb.y);
      acc.z += g * (p0.z + p1.z + bb.z);
      acc.w += g * (p0.w + p1.w + bb.w);
    }
  }
  *(float4*)&out[(size_t)tok * O_ + c] = acc;
}

// ---------- launch ----------
extern "C" void kernel_launch(void* const* d_in, const int* in_sizes, int n_in,
                              void* d_out, int out_size, void* d_ws, size_t ws_size,
                              hipStream_t stream) {
  const float* x     = (const float*)d_in[0];
  const float* wg    = (const float*)d_in[1];
  const float* w1    = (const float*)d_in[2];
  const float* b1    = (const float*)d_in[3];
  const float* g_ln  = (const float*)d_in[4];
  const float* b_ln  = (const float*)d_in[5];
  const float* w2    = (const float*)d_in[6];
  const float* b2    = (const float*)d_in[7];
  float* out = (float*)d_out;
  float* out_logits = out + (size_t)NTOK * O_;

  char* wsb = (char*)d_ws;
  unsigned short* xb   = (unsigned short*)(wsb + 0);          // 8,388,608 B
  unsigned short* w1t  = (unsigned short*)(wsb + 8388608);    // 33,554,432 B (reused as part)
  unsigned short* w2t  = (unsigned short*)(wsb + 41943040);   // 33,554,432 B
  unsigned short* hbuf = (unsigned short*)(wsb + 75497472);   // 16,777,216 B
  float* probs = (float*)(wsb + 92274688);                    // 131,072 B
  int*   sel   = (int*)  (wsb + 92405760);                    // 16,384 B
  float* gate  = (float*)(wsb + 92422144);                    // 16,384 B
  int*   entry = (int*)  (wsb + 92438528);                    // 131,072 B
  float* part  = (float*)(wsb + 8388608);                     // aliases w1t (dead after gemm1)

  hipMemsetAsync(entry, 0, (size_t)NTOK * E_ * sizeof(int), stream);

  gating_kernel<<<NTOK / 4, 256, 0, stream>>>(x, wg, out_logits, probs, xb);
  transpose_cvt_kernel<<<dim3(F_ / 64, D_ / 64, E_), 256, 0, stream>>>(w1, w1t, D_, F_); // -> [F][D]
  transpose_cvt_kernel<<<dim3(O_ / 64, F_ / 64, E_), 256, 0, stream>>>(w2, w2t, F_, O_); // -> [O][F]
  topk_kernel<<<2 * E_ * 8, 256, 0, stream>>>(out_logits, probs, sel, gate, entry);
  gemm1_kernel<<<(F_ / BN) * (ROWS / BM) * E_, 256, 0, stream>>>(xb, w1t, b1, sel, hbuf);
  ln_kernel<<<E_ * ROWS, 256, 0, stream>>>(hbuf, g_ln, b_ln);
  gemm2_partial_kernel<<<2048, 256, 0, stream>>>(hbuf, w2t, part);
  combine_kernel<<<NTOK, 256, 0, stream>>>(part, entry, gate, b2, out);
}

// Round 11
// 151.800 us; speedup vs baseline: 1.4118x; 1.0237x over previous
//
#include <hip/hip_runtime.h>
#include <cstdint>
#include <cstddef>

typedef __attribute__((ext_vector_type(8))) short bf16x8;
typedef __attribute__((ext_vector_type(4))) float f32x4;

#define S_    2048
#define D_    1024
#define F_    2048
#define O_    1024
#define E_    8
#define KCAP  256
#define ROWS  512           // 2 batches * KCAP per expert
#define NTOK  4096          // B*S

#define BM 64
#define BN 64
#define BK 64
#define TILE_ELEMS (BM * BK)

// ---------- bf16 helpers ----------
__device__ __forceinline__ unsigned short f2bf(float f) {
  unsigned int u = __float_as_uint(f);
  u = (u + 0x7fffu + ((u >> 16) & 1u)) >> 16;   // RNE
  return (unsigned short)u;
}
__device__ __forceinline__ float bf2f(unsigned short h) {
  return __uint_as_float(((unsigned int)h) << 16);
}

// ---------- async global->LDS, 16B per lane, wave-uniform LDS base ----------
__device__ __forceinline__ void gload16(void* lds, const void* g) {
  auto gp = (__attribute__((address_space(1))) unsigned int*)(uintptr_t)g;
  auto lp = (__attribute__((address_space(3))) unsigned int*)(unsigned int)(uintptr_t)lds;
  __builtin_amdgcn_global_load_lds(gp, lp, 16, 0, 0);
}

// ---------- gating: logits (fp64 accum) + softmax probs + x->bf16 ----------
__global__ void gating_kernel(const float* __restrict__ x, const float* __restrict__ wg,
                              float* __restrict__ logits, float* __restrict__ probs,
                              unsigned short* __restrict__ xb) {
  const int wave = threadIdx.x >> 6, lane = threadIdx.x & 63;
  const int t = blockIdx.x * 4 + wave;
  const float* xr = x + (size_t)t * D_;
  double acc[8] = {0, 0, 0, 0, 0, 0, 0, 0};
  const int d0 = lane * 16;
#pragma unroll
  for (int i = 0; i < 4; i++) {
    float4 xv = *(const float4*)&xr[d0 + i * 4];
    union { ushort4 u4; unsigned short u[4]; } cv;
    cv.u[0] = f2bf(xv.x); cv.u[1] = f2bf(xv.y); cv.u[2] = f2bf(xv.z); cv.u[3] = f2bf(xv.w);
    *(ushort4*)&xb[(size_t)t * D_ + d0 + i * 4] = cv.u4;
    float xs[4] = {xv.x, xv.y, xv.z, xv.w};
#pragma unroll
    for (int j = 0; j < 4; j++) {
      const float4* wr = (const float4*)&wg[(size_t)(d0 + i * 4 + j) * 8];
      float4 w0 = wr[0], w1v = wr[1];
      double xd = (double)xs[j];
      acc[0] += xd * (double)w0.x;  acc[1] += xd * (double)w0.y;
      acc[2] += xd * (double)w0.z;  acc[3] += xd * (double)w0.w;
      acc[4] += xd * (double)w1v.x; acc[5] += xd * (double)w1v.y;
      acc[6] += xd * (double)w1v.z; acc[7] += xd * (double)w1v.w;
    }
  }
#pragma unroll
  for (int off = 32; off; off >>= 1) {
#pragma unroll
    for (int e = 0; e < 8; e++) acc[e] += __shfl_down(acc[e], off);
  }
  if (lane == 0) {
    double m = acc[0];
    for (int e = 1; e < 8; e++) m = acc[e] > m ? acc[e] : m;
    double p[8]; double s = 0;
    for (int e = 0; e < 8; e++) { p[e] = exp(acc[e] - m); s += p[e]; }
    const double inv = 1.0 / s;
    for (int e = 0; e < 8; e++) {
      logits[(size_t)t * 8 + e] = (float)acc[e];
      probs [(size_t)t * 8 + e] = (float)(p[e] * inv);
    }
  }
}

// ---------- per-expert transpose + fp32->bf16: out[C][R] = in[R][C] ----------
__global__ void transpose_cvt_kernel(const float* __restrict__ in, unsigned short* __restrict__ out,
                                     const int R, const int C) {
  __shared__ float t[64][65];
  const int e = blockIdx.z;
  const float* inp = in + (size_t)e * R * C;
  unsigned short* outp = out + (size_t)e * R * C;
  const int r0 = blockIdx.y * 64, c0 = blockIdx.x * 64;
  const int tid = threadIdx.x;
  const int lr = tid >> 4;          // 0..15
  const int lc = (tid & 15) * 4;    // 0..60
#pragma unroll
  for (int i = 0; i < 4; i++) {
    const int r = lr + i * 16;
    const float4 v = *(const float4*)&inp[(size_t)(r0 + r) * C + c0 + lc];
    t[r][lc] = v.x; t[r][lc + 1] = v.y; t[r][lc + 2] = v.z; t[r][lc + 3] = v.w;
  }
  __syncthreads();
#pragma unroll
  for (int i = 0; i < 4; i++) {
    const int oc = lr + i * 16;     // output row (a C-index)
    union { ushort4 u4; unsigned short u[4]; } u;
#pragma unroll
    for (int j = 0; j < 4; j++) u.u[j] = f2bf(t[lc + j][oc]);
    *(ushort4*)&outp[(size_t)(c0 + oc) * R + r0 + lc] = u.u4;
  }
}

// ---------- expert-choice top-k + deterministic per-token inverse index ----------
// Grid covers every (b,e,s) exactly once -> entry written unconditionally (no memset).
__global__ void topk_kernel(const float* __restrict__ logits, const float* __restrict__ probs,
                            int* __restrict__ sel, float* __restrict__ gate,
                            int* __restrict__ entry) {    // entry[tok][e] = row+1 (0 = absent)
  __shared__ unsigned int keys[S_];
  const int idx = blockIdx.x;       // 0..127 : (b,e) x 8 segments
  const int seg = idx & 7;
  const int be = idx >> 3;          // 0..15
  const int b = be >> 3;            // 0..1
  const int e = be & 7;
  const int tid = threadIdx.x;
  for (int i = tid; i < S_; i += 256) {
    unsigned int u = __float_as_uint(logits[((size_t)(b * S_ + i)) * E_ + e]);
    keys[i] = u ^ ((u & 0x80000000u) ? 0xFFFFFFFFu : 0x80000000u);
  }
  __syncthreads();
  const int s = seg * 256 + tid;
  const unsigned int vk = keys[s];
  const int wave = tid >> 6;
  const int W0 = seg * 256 + wave * 64;
  int rank = 0;
#pragma unroll 4
  for (int i = 0; i < W0; i += 4) {
    const uint4 kv = *(const uint4*)&keys[i];
    rank += (kv.x >= vk) + (kv.y >= vk) + (kv.z >= vk) + (kv.w >= vk);
  }
#pragma unroll
  for (int j = 0; j < 64; j++) {
    const int i = W0 + j;
    const unsigned int kv = keys[i];
    rank += (kv > vk) || (kv == vk && i < s);
  }
#pragma unroll 4
  for (int i = W0 + 64; i < S_; i += 4) {
    const uint4 kv = *(const uint4*)&keys[i];
    rank += (kv.x > vk) + (kv.y > vk) + (kv.z > vk) + (kv.w > vk);
  }
  const int tok = b * S_ + s;
  if (rank < KCAP) {
    const int row = b * KCAP + rank;
    sel  [e * ROWS + row] = tok;
    gate [e * ROWS + row] = probs[(size_t)tok * E_ + e];
    entry[tok * E_ + e]   = row + 1;
  } else {
    entry[tok * E_ + e]   = 0;
  }
}

// ====================== GEMM1 (D1): single-buffer, 8 blocks/CU ======================
// 64x64x64, 4 waves, 16KB LDS single-buffer, gload16 + XOR swizzle, expert-per-XCD.
// Inter-block TLP (32 waves/CU) covers the per-step vmcnt(0) drain.
__global__ __launch_bounds__(256, 8) void gemm1_kernel(
    const unsigned short* __restrict__ xb, const unsigned short* __restrict__ w1t,
    const float* __restrict__ b1, const int* __restrict__ sel,
    unsigned short* __restrict__ hbuf) {
  __shared__ unsigned short As[TILE_ELEMS];   // 8 KB
  __shared__ unsigned short Bs[TILE_ELEMS];   // 8 KB
  const int bid = blockIdx.x;
  const int lid = (bid & 7) * 256 + (bid >> 3);
  const int e   = lid >> 8;
  const int rem = lid & 255;
  const int n0  = (rem >> 3) * BN;
  const int m0  = (rem & 7) * BM;
  const int tid = threadIdx.x;
  const int wave = tid >> 6, lane = tid & 63;
  const int wr = wave >> 1, wc = wave & 1;

  const int srow = lane >> 3;
  const int schunk = (lane & 7) ^ srow;
  const unsigned short* asrc[2];
  const unsigned short* bsrc[2];
#pragma unroll
  for (int j = 0; j < 2; j++) {
    const int r = wave * 16 + j * 8 + srow;
    const int tok = sel[e * ROWS + m0 + r];
    asrc[j] = xb + (size_t)tok * D_ + schunk * 8;
    bsrc[j] = w1t + ((size_t)e * F_ + n0 + r) * D_ + schunk * 8;
  }

  f32x4 acc[2][2];
#pragma unroll
  for (int mi = 0; mi < 2; mi++)
#pragma unroll
    for (int nj = 0; nj < 2; nj++) acc[mi][nj] = (f32x4){0.f, 0.f, 0.f, 0.f};

  const int fr = lane & 15;

  for (int t = 0; t < D_ / BK; t++) {
    const int k0 = t * BK;
#pragma unroll
    for (int j = 0; j < 2; j++) {
      gload16(&As[(wave * 16 + j * 8) * BK], asrc[j] + k0);
      gload16(&Bs[(wave * 16 + j * 8) * BK], bsrc[j] + k0);
    }
    __syncthreads();                 // staging complete (implicit vmcnt(0))
    bf16x8 a[2][2], b[2][2];
#pragma unroll
    for (int kk = 0; kk < 2; kk++) {
      const int xch = ((kk * 4 + (lane >> 4)) ^ (lane & 7)) * 8;
#pragma unroll
      for (int mi = 0; mi < 2; mi++)
        a[kk][mi] = *(const bf16x8*)&As[(wr * 32 + mi * 16 + fr) * BK + xch];
#pragma unroll
      for (int nj = 0; nj < 2; nj++)
        b[kk][nj] = *(const bf16x8*)&Bs[(wc * 32 + nj * 16 + fr) * BK + xch];
    }
#pragma unroll
    for (int kk = 0; kk < 2; kk++)
#pragma unroll
      for (int mi = 0; mi < 2; mi++)
#pragma unroll
        for (int nj = 0; nj < 2; nj++)
          acc[mi][nj] = __builtin_amdgcn_mfma_f32_16x16x32_bf16(a[kk][mi], b[kk][nj], acc[mi][nj], 0, 0, 0);
    __syncthreads();                 // all waves done reading before next overwrite
  }

  const int lr = (lane >> 4) * 4;
#pragma unroll
  for (int mi = 0; mi < 2; mi++)
#pragma unroll
    for (int nj = 0; nj < 2; nj++)
#pragma unroll
      for (int rg = 0; rg < 4; rg++) {
        const int row = m0 + wr * 32 + mi * 16 + lr + rg;
        const int col = n0 + wc * 32 + nj * 16 + fr;
        float v = acc[mi][nj][rg] + b1[e * F_ + col];
        v = 0.5f * v * (1.0f + erff(v * 0.70710678118654752f));   // exact GELU
        hbuf[((size_t)e * ROWS + row) * F_ + col] = f2bf(v);
      }
}

// ---------- row LayerNorm over F_, in place on bf16 h ----------
__global__ void ln_kernel(unsigned short* __restrict__ hbuf,
                          const float* __restrict__ g_ln, const float* __restrict__ b_ln) {
  const int row = blockIdx.x;          // 0..E_*ROWS-1
  const int e = row >> 9;
  unsigned short* hr = hbuf + (size_t)row * F_;
  const int tid = threadIdx.x;
  union { bf16x8 v; unsigned short u[8]; } u;
  u.v = *(const bf16x8*)&hr[tid * 8];
  float vals[8]; float s1 = 0.f, s2 = 0.f;
#pragma unroll
  for (int j = 0; j < 8; j++) { float f = bf2f(u.u[j]); vals[j] = f; s1 += f; s2 += f * f; }
#pragma unroll
  for (int off = 32; off; off >>= 1) { s1 += __shfl_down(s1, off); s2 += __shfl_down(s2, off); }
  __shared__ float rs[8];
  const int wave = tid >> 6, lane = tid & 63;
  if (lane == 0) { rs[wave] = s1; rs[wave + 4] = s2; }
  __syncthreads();
  const float t1 = rs[0] + rs[1] + rs[2] + rs[3];
  const float t2 = rs[4] + rs[5] + rs[6] + rs[7];
  const float mu = t1 * (1.f / F_);
  const float var = t2 * (1.f / F_) - mu * mu;   // biased var (jnp.var)
  const float rstd = rsqrtf(var + 1e-5f);
  const float4* gl4 = (const float4*)(g_ln + (size_t)e * F_ + tid * 8);
  const float4* bl4 = (const float4*)(b_ln + (size_t)e * F_ + tid * 8);
  float4 g0 = gl4[0], g1 = gl4[1], bb0 = bl4[0], bb1 = bl4[1];
  float gs[8] = {g0.x, g0.y, g0.z, g0.w, g1.x, g1.y, g1.z, g1.w};
  float bs[8] = {bb0.x, bb0.y, bb0.z, bb0.w, bb1.x, bb1.y, bb1.z, bb1.w};
  union { bf16x8 v; unsigned short u[8]; } o;
#pragma unroll
  for (int j = 0; j < 8; j++)
    o.u[j] = f2bf((vals[j] - mu) * rstd * gs[j] + bs[j]);
  *(bf16x8*)&hr[tid * 8] = o.v;
}

// ====================== GEMM2 partial: split-K x2, D1 structure, plain stores ======================
// part[khalf][e*ROWS+row][col]; 2048 blocks = 8 blocks/CU, no atomics.
__global__ __launch_bounds__(256, 8) void gemm2_partial_kernel(
    const unsigned short* __restrict__ hbuf, // [E][ROWS][F_]
    const unsigned short* __restrict__ w2t,  // [E][O_][F_]
    float* __restrict__ part) {              // [2][E_*ROWS][O_]
  __shared__ unsigned short As[TILE_ELEMS];
  __shared__ unsigned short Bs[TILE_ELEMS];
  const int bid = blockIdx.x;
  const int lid = (bid & 7) * 256 + (bid >> 3);   // 8 XCDs x 256; expert-per-XCD
  const int e     = lid >> 8;
  const int rem   = lid & 255;
  const int khalf = rem & 1;
  const int m0    = ((rem >> 1) & 7) * BM;
  const int n0    = (rem >> 4) * BN;              // 16 O panels
  const int koff  = khalf * (F_ / 2);
  const int tid = threadIdx.x;
  const int wave = tid >> 6, lane = tid & 63;
  const int wr = wave >> 1, wc = wave & 1;

  const int srow = lane >> 3;
  const int schunk = (lane & 7) ^ srow;
  const unsigned short* asrc[2];
  const unsigned short* bsrc[2];
#pragma unroll
  for (int j = 0; j < 2; j++) {
    const int r = wave * 16 + j * 8 + srow;
    asrc[j] = hbuf + ((size_t)e * ROWS + m0 + r) * F_ + koff + schunk * 8;
    bsrc[j] = w2t + ((size_t)e * O_ + n0 + r) * F_ + koff + schunk * 8;
  }

  f32x4 acc[2][2];
#pragma unroll
  for (int mi = 0; mi < 2; mi++)
#pragma unroll
    for (int nj = 0; nj < 2; nj++) acc[mi][nj] = (f32x4){0.f, 0.f, 0.f, 0.f};

  const int fr = lane & 15;

  for (int t = 0; t < (F_ / 2) / BK; t++) {   // 16 steps
    const int k0 = t * BK;
#pragma unroll
    for (int j = 0; j < 2; j++) {
      gload16(&As[(wave * 16 + j * 8) * BK], asrc[j] + k0);
      gload16(&Bs[(wave * 16 + j * 8) * BK], bsrc[j] + k0);
    }
    __syncthreads();
    bf16x8 a[2][2], b[2][2];
#pragma unroll
    for (int kk = 0; kk < 2; kk++) {
      const int xch = ((kk * 4 + (lane >> 4)) ^ (lane & 7)) * 8;
#pragma unroll
      for (int mi = 0; mi < 2; mi++)
        a[kk][mi] = *(const bf16x8*)&As[(wr * 32 + mi * 16 + fr) * BK + xch];
#pragma unroll
      for (int nj = 0; nj < 2; nj++)
        b[kk][nj] = *(const bf16x8*)&Bs[(wc * 32 + nj * 16 + fr) * BK + xch];
    }
#pragma unroll
    for (int kk = 0; kk < 2; kk++)
#pragma unroll
      for (int mi = 0; mi < 2; mi++)
#pragma unroll
        for (int nj = 0; nj < 2; nj++)
          acc[mi][nj] = __builtin_amdgcn_mfma_f32_16x16x32_bf16(a[kk][mi], b[kk][nj], acc[mi][nj], 0, 0, 0);
    __syncthreads();
  }

  float* pbase = part + (size_t)khalf * (E_ * ROWS) * O_;
  const int lr = (lane >> 4) * 4;
#pragma unroll
  for (int mi = 0; mi < 2; mi++)
#pragma unroll
    for (int rg = 0; rg < 4; rg++) {
      const int row = m0 + wr * 32 + mi * 16 + lr + rg;
#pragma unroll
      for (int nj = 0; nj < 2; nj++) {
        const int col = n0 + wc * 32 + nj * 16 + fr;
        pbase[((size_t)(e * ROWS) + row) * O_ + col] = acc[mi][nj][rg];
      }
    }
}

// ---------- combine: out[tok] = sum_e gate * (p0 + p1 + b2[e]) ; atomic-free ----------
__global__ void combine_kernel(const float* __restrict__ part, const int* __restrict__ entry,
                               const float* __restrict__ gate, const float* __restrict__ b2,
                               float* __restrict__ out) {
  const int tok = blockIdx.x;
  const int c = threadIdx.x * 4;
  float4 acc = {0.f, 0.f, 0.f, 0.f};
#pragma unroll
  for (int e = 0; e < E_; e++) {
    const int r1 = entry[tok * E_ + e];
    if (r1) {
      const int idx = e * ROWS + (r1 - 1);
      const float g = gate[idx];
      const float4 p0 = *(const float4*)&part[(size_t)idx * O_ + c];
      const float4 p1 = *(const float4*)&part[(size_t)(E_ * ROWS + idx) * O_ + c];
      const float4 bb = *(const float4*)&b2[e * O_ + c];
      acc.x += g * (p0.x + p1.x + bb.x);
      acc.y += g * (p0.y + p1.y + bb.y);
      acc.z += g * (p0.z + p1.z + bb.z);
      acc.w += g * (p0.w + p1.w + bb.w);
    }
  }
  *(float4*)&out[(size_t)tok * O_ + c] = acc;
}

// ---------- launch ----------
extern "C" void kernel_launch(void* const* d_in, const int* in_sizes, int n_in,
                              void* d_out, int out_size, void* d_ws, size_t ws_size,
                              hipStream_t stream) {
  const float* x     = (const float*)d_in[0];
  const float* wg    = (const float*)d_in[1];
  const float* w1    = (const float*)d_in[2];
  const float* b1    = (const float*)d_in[3];
  const float* g_ln  = (const float*)d_in[4];
  const float* b_ln  = (const float*)d_in[5];
  const float* w2    = (const float*)d_in[6];
  const float* b2    = (const float*)d_in[7];
  float* out = (float*)d_out;
  float* out_logits = out + (size_t)NTOK * O_;

  char* wsb = (char*)d_ws;
  unsigned short* xb   = (unsigned short*)(wsb + 0);          // 8,388,608 B
  unsigned short* w1t  = (unsigned short*)(wsb + 8388608);    // 33,554,432 B (reused as part)
  unsigned short* w2t  = (unsigned short*)(wsb + 41943040);   // 33,554,432 B
  unsigned short* hbuf = (unsigned short*)(wsb + 75497472);   // 16,777,216 B
  float* probs = (float*)(wsb + 92274688);                    // 131,072 B
  int*   sel   = (int*)  (wsb + 92405760);                    // 16,384 B
  float* gate  = (float*)(wsb + 92422144);                    // 16,384 B
  int*   entry = (int*)  (wsb + 92438528);                    // 131,072 B
  float* part  = (float*)(wsb + 8388608);                     // aliases w1t (dead after gemm1)

  gating_kernel<<<NTOK / 4, 256, 0, stream>>>(x, wg, out_logits, probs, xb);
  transpose_cvt_kernel<<<dim3(F_ / 64, D_ / 64, E_), 256, 0, stream>>>(w1, w1t, D_, F_); // -> [F][D]
  transpose_cvt_kernel<<<dim3(O_ / 64, F_ / 64, E_), 256, 0, stream>>>(w2, w2t, F_, O_); // -> [O][F]
  topk_kernel<<<2 * E_ * 8, 256, 0, stream>>>(out_logits, probs, sel, gate, entry);
  gemm1_kernel<<<(F_ / BN) * (ROWS / BM) * E_, 256, 0, stream>>>(xb, w1t, b1, sel, hbuf);
  ln_kernel<<<E_ * ROWS, 256, 0, stream>>>(hbuf, g_ln, b_ln);
  gemm2_partial_kernel<<<2048, 256, 0, stream>>>(hbuf, w2t, part);
  combine_kernel<<<NTOK, 256, 0, stream>>>(part, entry, gate, b2, out);
}